// Round 12
// baseline (398.899 us; speedup 1.0000x reference)
//
#include <hip/hip_runtime.h>
#include <hip/hip_cooperative_groups.h>
#include <math.h>

namespace cg = cooperative_groups;

// Problem dims (fixed by the reference)
#define ED 16      // EDGE_DIM
#define HD 32      // HIDDEN (== NODE_DIM == in_channels)
#define OD 32      // OUT_DIM
#define KD 1024    // HD*OD
#define EPB 512    // edges per tile (one 512-thread block processes one tile)
#define TPW 4      // 16-edge MFMA tiles per wave
#define HPAD 34    // LDS row stride (halfwords): odd word-stride -> conflict-free
#define CAP 32     // bucket capacity per node (deg ~ Poisson(4))

typedef float  f32x4  __attribute__((ext_vector_type(4)));
typedef float  v4f    __attribute__((ext_vector_type(4)));
typedef short  bf16x8 __attribute__((ext_vector_type(8)));
typedef short  bf16x4 __attribute__((ext_vector_type(4)));

// LDS layout (edge phase); gather phase reuses [0, 34816) for rootS/biasS/xsh.
constexpr int LOFF_HX  = 0;                      // hHi [EPB][HPAD] hw; xS overlay
constexpr int LOFF_WHI = EPB * HPAD * 2;         // 34816: wLhi 32 KB (o-half frags)
constexpr int LOFF_W1T = LOFF_WHI + 32768;       // 67584: W1fT 2048 B
constexpr int LOFF_B1  = LOFF_W1T + 2048;        // 69632: b1f 128 B
constexpr int LOFF_BF  = LOFF_B1 + 128;          // 69760: bfold half 2048 B
constexpr int LOFF_DST = LOFF_BF + 2048;         // 71808: dstS 2048 B
constexpr int LDS_TOTAL= LOFF_DST + 2048;        // 73856 B -> 2 blocks/CU

__device__ inline unsigned short bf16_rne(float v) {
    unsigned int u = __float_as_uint(v);
    return (unsigned short)((u + 0x7FFFu + ((u >> 16) & 1u)) >> 16);
}

// ---------------------------------------------------------------------------
// Per-block weight fold: raw W1/W2 + BN params (global, read-only) -> LDS.
// o-half s only. W2 read pattern: 16 lanes of a quad-group read 16 consecutive
// k for fixed j -> 64B lines, L2-hot after first touches (W2 = 128 KB total).
// ---------------------------------------------------------------------------
__device__ __forceinline__ void stage_weights(
    int t, int s, unsigned char* smem,
    const float* __restrict__ W1, const float* __restrict__ b1,
    const float* __restrict__ g1, const float* __restrict__ be1,
    const float* __restrict__ m1, const float* __restrict__ v1,
    const float* __restrict__ W2, const float* __restrict__ b2,
    const float* __restrict__ g2, const float* __restrict__ be2,
    const float* __restrict__ m2, const float* __restrict__ v2)
{
    float* w1t = (float*)(smem + LOFF_W1T);
    float* b1s = (float*)(smem + LOFF_B1);
    float* bfL = (float*)(smem + LOFF_BF);
    unsigned short* wLhi = (unsigned short*)(smem + LOFF_WHI);

    {   // W1fT [c][j], 512 entries, one per thread
        int c = t >> 4, j = t & 15;
        float sc = g1[c] / sqrtf(v1[c] + 1e-5f);
        w1t[t] = W1[j * HD + c] * sc;
    }
    if (t < HD) {
        float sc = g1[t] / sqrtf(v1[t] + 1e-5f);
        b1s[t] = b1[t] * sc + be1[t] - m1[t] * sc;
    }
    {   // bfold half: bfL[i*16+m], k = (2i+s)*16+m
        int i = t >> 4, m = t & 15;
        int k = (2 * i + s) * 16 + m;
        float sc = g2[k] / sqrtf(v2[k] + 1e-5f);
        bfL[t] = b2[k] * sc + be2[k] - m2[k] * sc;
    }
#pragma unroll
    for (int p = 0; p < 4; ++p) {   // wLhi frag-linear, 4 x 8-bf16 chunks/thread
        int c = t + p * 512;                       // chunk: i = c>>6, lane = c&63
        int i = c >> 6, ln = c & 63;
        int m = ln & 15, quad = ln >> 4;
        int k = (2 * i + s) * 16 + m;
        float sc = g2[k] / sqrtf(v2[k] + 1e-5f);
        bf16x8 w;
#pragma unroll
        for (int idx = 0; idx < 8; ++idx) {
            int j = quad * 8 + idx;
            w[idx] = (short)bf16_rne(W2[j * KD + k] * sc);
        }
        *(bf16x8*)(wLhi + (size_t)c * 8) = w;
    }
}

// ---------------------------------------------------------------------------
// One 512-edge tile (r11 body): layer1 -> bf16 h in LDS -> MFMA loop ->
// bf16 msg store + bucket insert. Assumes weights staged (stable in LDS).
// 4 __syncthreads per tile; safe for back-to-back tiles (sync A guards the
// hHi/xS overlay against the previous tile's main-loop xS reads).
// ---------------------------------------------------------------------------
__device__ __forceinline__ void edge_tile(
    int t, int s, int tileBase, unsigned char* smem,
    const float* __restrict__ x, const int* __restrict__ eidx,
    const float* __restrict__ ea_g,
    unsigned short* __restrict__ msgb, int* __restrict__ cnt,
    int* __restrict__ bucket, int nE)
{
    unsigned short* hHi = (unsigned short*)(smem + LOFF_HX);
    unsigned short* xS  = (unsigned short*)(smem + LOFF_HX);   // overlay
    const unsigned short* wLhi = (const unsigned short*)(smem + LOFF_WHI);
    const float* w1t = (const float*)(smem + LOFF_W1T);
    const float* b1s = (const float*)(smem + LOFF_B1);
    const float* bfL = (const float*)(smem + LOFF_BF);
    int* dstS = (int*)(smem + LOFF_DST);

    int e = tileBase + t;
    int ec = (e < nE) ? e : (nE - 1);
    int my_src = __builtin_nontemporal_load(eidx + ec);
    int my_dst = __builtin_nontemporal_load(eidx + nE + ec);

    const v4f* xrow_p = (const v4f*)(x + (size_t)my_src * HD);
    v4f xrow[8];
#pragma unroll
    for (int q = 0; q < 8; ++q) xrow[q] = xrow_p[q];

    const v4f* eap = (const v4f*)(ea_g + (size_t)ec * ED);
    v4f a0 = __builtin_nontemporal_load(eap + 0);
    v4f a1 = __builtin_nontemporal_load(eap + 1);
    v4f a2 = __builtin_nontemporal_load(eap + 2);
    v4f a3 = __builtin_nontemporal_load(eap + 3);

    dstS[t] = my_dst;

    // ---- layer 1 (uses staged w1t/b1s; stable across tiles) ----
    float hreg[HD];
#pragma unroll
    for (int c = 0; c < HD; ++c) {
        const v4f* r4 = (const v4f*)(w1t + c * ED);
        v4f w0 = r4[0], w1 = r4[1], w2 = r4[2], w3 = r4[3];
        float acc = b1s[c];
        acc = fmaf(a0.x, w0.x, acc); acc = fmaf(a0.y, w0.y, acc);
        acc = fmaf(a0.z, w0.z, acc); acc = fmaf(a0.w, w0.w, acc);
        acc = fmaf(a1.x, w1.x, acc); acc = fmaf(a1.y, w1.y, acc);
        acc = fmaf(a1.z, w1.z, acc); acc = fmaf(a1.w, w1.w, acc);
        acc = fmaf(a2.x, w2.x, acc); acc = fmaf(a2.y, w2.y, acc);
        acc = fmaf(a2.z, w2.z, acc); acc = fmaf(a2.w, w2.w, acc);
        acc = fmaf(a3.x, w3.x, acc); acc = fmaf(a3.y, w3.y, acc);
        acc = fmaf(a3.z, w3.z, acc); acc = fmaf(a3.w, w3.w, acc);
        hreg[c] = fmaxf(acc, 0.01f * acc);
    }

    __syncthreads();   // A: previous tile's xS reads complete

#pragma unroll
    for (int ch = 0; ch < 4; ++ch) {
        bf16x8 phi;
#pragma unroll
        for (int u = 0; u < 8; ++u)
            phi[u] = (short)bf16_rne(hreg[ch * 8 + u]);
        *(bf16x8*)(hHi + t * HPAD + ch * 8) = phi;
    }
    __syncthreads();   // B: h ready

    const int wave = t >> 6;
    const int lane = t & 63;
    const int n = lane & 15;
    const int quad = lane >> 4;
    const int ebase = wave * 64;

    bf16x8 bHi[TPW];
#pragma unroll
    for (int tt = 0; tt < TPW; ++tt) {
        int edge = ebase + tt * 16 + n;
        bHi[tt] = *(const bf16x8*)(hHi + edge * HPAD + quad * 8);
    }

    int xdst[TPW];
    bool evalid[TPW];
    int xoff[TPW];
    int geid[TPW];
#pragma unroll
    for (int tt = 0; tt < TPW; ++tt) {
        int le = ebase + tt * 16 + n;
        geid[tt] = tileBase + le;
        evalid[tt] = geid[tt] < nE;
        xdst[tt] = dstS[le];
        xoff[tt] = le * HPAD;
    }

    __syncthreads();   // C: h reads done

#pragma unroll
    for (int ch = 0; ch < 4; ++ch) {
        bf16x8 px;
#pragma unroll
        for (int u = 0; u < 8; ++u) {
            int q = ch * 2 + (u >> 2);
            px[u] = (short)bf16_rne(xrow[q][u & 3]);
        }
        *(bf16x8*)(xS + t * HPAD + ch * 8) = px;
    }
    __syncthreads();   // D: xS ready

    f32x4 msg[TPW];
#pragma unroll
    for (int tt = 0; tt < TPW; ++tt)
        msg[tt] = (f32x4){0.f, 0.f, 0.f, 0.f};

#pragma unroll 4
    for (int i = 0; i < HD; ++i) {
        const bf16x8 cH = *(const bf16x8*)(wLhi + i * 512 + lane * 8);
        const f32x4 b0 = *(const f32x4*)(bfL + i * 16 + quad * 4);
        float xv[TPW];
#pragma unroll
        for (int tt = 0; tt < TPW; ++tt) {
            unsigned int u = xS[xoff[tt] + i];
            xv[tt] = __uint_as_float(u << 16);
        }
#pragma unroll
        for (int tt = 0; tt < TPW; ++tt) {
            f32x4 c = b0;
            c = __builtin_amdgcn_mfma_f32_16x16x32_bf16(cH, bHi[tt], c, 0, 0, 0);
            f32x4 w = __builtin_elementwise_max(c, 0.01f * c);   // LeakyReLU
            f32x4 xs = {xv[tt], xv[tt], xv[tt], xv[tt]};
            msg[tt] = __builtin_elementwise_fma(xs, w, msg[tt]);
        }
    }

    // bf16 msg store + bucket insert (owner: s==0 && quad==0)
#pragma unroll
    for (int tt = 0; tt < TPW; ++tt) {
        if (!evalid[tt]) continue;
        bf16x4 pm;
#pragma unroll
        for (int r = 0; r < 4; ++r) pm[r] = (short)bf16_rne(msg[tt][r]);
        __builtin_nontemporal_store(pm,
            (bf16x4*)(msgb + (size_t)geid[tt] * OD + s * 16 + quad * 4));
    }
    if (s == 0 && quad == 0) {
#pragma unroll
        for (int tt = 0; tt < TPW; ++tt) {
            if (!evalid[tt]) continue;
            int pos = atomicAdd(cnt + xdst[tt], 1);
            if (pos < CAP) bucket[(size_t)xdst[tt] * CAP + pos] = geid[tt];
        }
    }
}

// ---------------------------------------------------------------------------
// Gather+root phase: out[v][ch] = bias + x[v]@root[:,ch] + sum(bucket msgs).
// 512 threads = 16 nodes/group. Reuses smem [0,34816).
// ---------------------------------------------------------------------------
__device__ __forceinline__ void gather_phase(
    int t, unsigned char* smem,
    const float* __restrict__ x, const float* __restrict__ root,
    const float* __restrict__ bias,
    const unsigned short* __restrict__ msgb,
    const int* __restrict__ bucket, const int* __restrict__ cnt,
    const int* __restrict__ eidx,
    float* __restrict__ out, int nN, int nE, int bx, int gdx)
{
    float* rootS = (float*)smem;                 // 4096 B
    float* biasS = (float*)(smem + 4096);        // 128 B
    float* xsh   = (float*)(smem + 4224);        // [16][33] f32

    if (t < 256)      ((v4f*)rootS)[t] = ((const v4f*)root)[t];
    else if (t < 264) ((v4f*)biasS)[t - 256] = ((const v4f*)bias)[t - 256];

    int nGroups = (nN + 15) / 16;
    for (int grp = bx; grp < nGroups; grp += gdx) {
        __syncthreads();   // rootS ready (1st) / prev xsh reads done
        if (t < 128) {
            int nl = t >> 3, q = t & 7;
            int node = grp * 16 + nl;
            if (node >= nN) node = nN - 1;
            v4f v = ((const v4f*)(x + (size_t)node * HD))[q];
            xsh[nl * 33 + 4 * q + 0] = v.x;
            xsh[nl * 33 + 4 * q + 1] = v.y;
            xsh[nl * 33 + 4 * q + 2] = v.z;
            xsh[nl * 33 + 4 * q + 3] = v.w;
        }
        __syncthreads();

        int nl = t >> 5, ch = t & 31;
        int v = grp * 16 + nl;
        if (v < nN) {
            float acc = biasS[ch];
#pragma unroll
            for (int i = 0; i < HD; ++i)
                acc = fmaf(xsh[nl * 33 + i], rootS[i * OD + ch], acc);
            int c = cnt[v];
            if (c <= CAP) {
                const int* bk = bucket + (size_t)v * CAP;
                for (int p = 0; p < c; ++p) {
                    int e = bk[p];
                    unsigned int u = msgb[(size_t)e * OD + ch];
                    acc += __uint_as_float(u << 16);
                }
            } else {   // pathological overflow: rescan dst list
                const int* dstp = eidx + nE;
                for (int e = 0; e < nE; ++e)
                    if (dstp[e] == v) {
                        unsigned int u = msgb[(size_t)e * OD + ch];
                        acc += __uint_as_float(u << 16);
                    }
            }
            __builtin_nontemporal_store(acc, out + (size_t)v * OD + ch);
        }
    }
}

// ---------------------------------------------------------------------------
// Single cooperative kernel: zero cnt -> stage weights -> edge tiles ->
// fence+grid.sync -> gather+root. Persistent blocks; s = blockIdx.x & 1.
// ---------------------------------------------------------------------------
__global__ __launch_bounds__(512, 4)
void fused_kernel(const float* __restrict__ x, const int* __restrict__ eidx,
                  const float* __restrict__ ea,
                  const float* __restrict__ W1, const float* __restrict__ b1,
                  const float* __restrict__ g1, const float* __restrict__ be1,
                  const float* __restrict__ m1, const float* __restrict__ v1,
                  const float* __restrict__ W2, const float* __restrict__ b2,
                  const float* __restrict__ g2, const float* __restrict__ be2,
                  const float* __restrict__ m2, const float* __restrict__ v2,
                  const float* __restrict__ root, const float* __restrict__ bias,
                  unsigned short* msgb, int* bucket, int* cnt,
                  float* out, int nN, int nE)
{
    __shared__ __align__(16) unsigned char smem[LDS_TOTAL];
    const int t = threadIdx.x;
    const int s = (int)blockIdx.x & 1;

    // zero cnt via memory-side atomics (coherent with later atomicAdds)
    for (int i = (int)blockIdx.x * 512 + t; i < nN; i += (int)gridDim.x * 512)
        atomicExch(cnt + i, 0);

    stage_weights(t, s, smem, W1, b1, g1, be1, m1, v1,
                  W2, b2, g2, be2, m2, v2);

    cg::this_grid().sync();   // cnt zeroed everywhere; weights block-local

    const int nTiles = (nE + EPB - 1) / EPB;
    for (int tile = (int)blockIdx.x >> 1; tile < nTiles; tile += (int)gridDim.x >> 1)
        edge_tile(t, s, tile * EPB, smem, x, eidx, ea, msgb, cnt, bucket, nE);

    __threadfence();          // device-scope release: msgb/bucket visible
    cg::this_grid().sync();

    gather_phase(t, smem, x, root, bias, msgb, bucket, cnt, eidx,
                 out, nN, nE, (int)blockIdx.x, (int)gridDim.x);
}

// ---------------------------------------------------------------------------
// Non-cooperative fallback path (same device code, 3 dispatches).
// ---------------------------------------------------------------------------
__global__ void zero_cnt_k(int* __restrict__ cnt, int nN)
{
    int i = blockIdx.x * blockDim.x + threadIdx.x;
    if (i < nN) cnt[i] = 0;
}

__global__ __launch_bounds__(512, 4)
void edge_k(const float* __restrict__ x, const int* __restrict__ eidx,
            const float* __restrict__ ea,
            const float* __restrict__ W1, const float* __restrict__ b1,
            const float* __restrict__ g1, const float* __restrict__ be1,
            const float* __restrict__ m1, const float* __restrict__ v1,
            const float* __restrict__ W2, const float* __restrict__ b2,
            const float* __restrict__ g2, const float* __restrict__ be2,
            const float* __restrict__ m2, const float* __restrict__ v2,
            unsigned short* msgb, int* cnt, int* bucket, int nE)
{
    __shared__ __align__(16) unsigned char smem[LDS_TOTAL];
    const int t = threadIdx.x;
    const int s = blockIdx.y;
    stage_weights(t, s, smem, W1, b1, g1, be1, m1, v1,
                  W2, b2, g2, be2, m2, v2);
    __syncthreads();
    edge_tile(t, s, (int)blockIdx.x * EPB, smem, x, eidx, ea, msgb, cnt, bucket, nE);
}

__global__ __launch_bounds__(512)
void gather_k(const float* __restrict__ x, const float* __restrict__ root,
              const float* __restrict__ bias,
              const unsigned short* __restrict__ msgb,
              const int* __restrict__ bucket, const int* __restrict__ cnt,
              const int* __restrict__ eidx,
              float* __restrict__ out, int nN, int nE)
{
    __shared__ __align__(16) unsigned char smem[4224 + 16 * 33 * 4];
    gather_phase(threadIdx.x, smem, x, root, bias, msgb, bucket, cnt, eidx,
                 out, nN, nE, (int)blockIdx.x, (int)gridDim.x);
}

// ---------------------------------------------------------------------------
// Zero-workspace fallback: raw per-edge VALU path with direct atomics.
// ---------------------------------------------------------------------------
__global__ void root_init_k(const float* __restrict__ x, const float* __restrict__ root,
                            const float* __restrict__ bias, float* __restrict__ out, int nN)
{
    int t = blockIdx.x * blockDim.x + threadIdx.x;
    if (t >= nN * OD) return;
    int o = t & (OD - 1);
    int n = t >> 5;
    const float* xr = x + (size_t)n * HD;
    float acc = bias[o];
#pragma unroll
    for (int i = 0; i < HD; ++i)
        acc = fmaf(xr[i], root[i * OD + o], acc);
    out[t] = acc;
}

__global__ __launch_bounds__(64)
void edge_raw_k(const float* __restrict__ x, const int* __restrict__ eidx,
                const float* __restrict__ ea_g,
                const float* __restrict__ W1, const float* __restrict__ b1,
                const float* __restrict__ g1, const float* __restrict__ be1,
                const float* __restrict__ m1, const float* __restrict__ v1,
                const float* __restrict__ W2, const float* __restrict__ b2,
                const float* __restrict__ g2, const float* __restrict__ be2,
                const float* __restrict__ m2, const float* __restrict__ v2,
                float* __restrict__ out, int nE)
{
    int e = blockIdx.x * 64 + threadIdx.x;
    if (e >= nE) return;
    const int obase = blockIdx.y * 16;
    int src = eidx[e];
    int dst = eidx[nE + e];
    float eav[ED];
#pragma unroll
    for (int j = 0; j < ED; ++j) eav[j] = ea_g[(size_t)e * ED + j];
    float h[HD];
#pragma unroll
    for (int c = 0; c < HD; ++c) {
        float acc = b1[c];
#pragma unroll
        for (int j = 0; j < ED; ++j) acc = fmaf(eav[j], W1[j * HD + c], acc);
        float sc = g1[c] / sqrtf(v1[c] + 1e-5f);
        acc = (acc - m1[c]) * sc + be1[c];
        h[c] = fmaxf(acc, 0.01f * acc);
    }
    float msg[16];
#pragma unroll
    for (int o = 0; o < 16; ++o) msg[o] = 0.f;
    const float* xj = x + (size_t)src * HD;
    for (int i = 0; i < HD; ++i) {
        float xv = xj[i];
#pragma unroll
        for (int oo = 0; oo < 16; ++oo) {
            int k = i * OD + obase + oo;
            float acc = b2[k];
#pragma unroll
            for (int j = 0; j < HD; ++j) acc = fmaf(h[j], W2[j * KD + k], acc);
            float sc = g2[k] / sqrtf(v2[k] + 1e-5f);
            acc = (acc - m2[k]) * sc + be2[k];
            float w = fmaxf(acc, 0.01f * acc);
            msg[oo] = fmaf(xv, w, msg[oo]);
        }
    }
    float* op = out + (size_t)dst * OD + obase;
#pragma unroll
    for (int oo = 0; oo < 16; ++oo) atomicAdd(op + oo, msg[oo]);
}

// ---------------------------------------------------------------------------
extern "C" void kernel_launch(void* const* d_in, const int* in_sizes, int n_in,
                              void* d_out, int out_size, void* d_ws, size_t ws_size,
                              hipStream_t stream)
{
    const float* x    = (const float*)d_in[0];
    const int*   eidx = (const int*)  d_in[1];
    const float* ea   = (const float*)d_in[2];
    const float* W1   = (const float*)d_in[4];
    const float* b1   = (const float*)d_in[5];
    const float* g1   = (const float*)d_in[6];
    const float* be1  = (const float*)d_in[7];
    const float* m1   = (const float*)d_in[8];
    const float* v1   = (const float*)d_in[9];
    const float* W2   = (const float*)d_in[10];
    const float* b2   = (const float*)d_in[11];
    const float* g2   = (const float*)d_in[12];
    const float* be2  = (const float*)d_in[13];
    const float* m2   = (const float*)d_in[14];
    const float* v2   = (const float*)d_in[15];
    const float* root = (const float*)d_in[16];
    const float* bias = (const float*)d_in[17];
    float* out = (float*)d_out;

    int nN = in_sizes[0] / HD;
    int nE = in_sizes[2] / ED;

    size_t msgB = (size_t)nE * OD * 2;                     // bf16 msg
    size_t OFF_BKT = (msgB + 15) & ~(size_t)15;
    size_t OFF_CNT = OFF_BKT + (size_t)nN * CAP * 4;
    size_t need = OFF_CNT + (size_t)nN * 4;

    if (ws_size >= need) {
        unsigned char* wsb = (unsigned char*)d_ws;
        unsigned short* msgb = (unsigned short*)wsb;
        int* bucket = (int*)(wsb + OFF_BKT);
        int* cnt    = (int*)(wsb + OFF_CNT);

        bool launched = false;
        int occ = 0;
        hipError_t e1 = hipOccupancyMaxActiveBlocksPerMultiprocessor(
            &occ, (const void*)fused_kernel, 512, 0);
        if (e1 == hipSuccess && occ > 0) {
            int dev = 0;
            hipGetDevice(&dev);
            hipDeviceProp_t prop;
            if (hipGetDeviceProperties(&prop, dev) == hipSuccess) {
                int grid = occ * prop.multiProcessorCount;
                grid &= ~1;                    // s = bx&1 pairing requires even
                if (grid >= 2) {
                    void* args[] = {
                        (void*)&x, (void*)&eidx, (void*)&ea,
                        (void*)&W1, (void*)&b1, (void*)&g1, (void*)&be1,
                        (void*)&m1, (void*)&v1,
                        (void*)&W2, (void*)&b2, (void*)&g2, (void*)&be2,
                        (void*)&m2, (void*)&v2,
                        (void*)&root, (void*)&bias,
                        (void*)&msgb, (void*)&bucket, (void*)&cnt,
                        (void*)&out, (void*)&nN, (void*)&nE };
                    hipError_t e3 = hipLaunchCooperativeKernel(
                        (const void*)fused_kernel, dim3(grid), dim3(512),
                        args, 0, stream);
                    launched = (e3 == hipSuccess);
                }
            }
        }
        if (!launched) {
            // 3-dispatch fallback, same device code
            zero_cnt_k<<<(nN + 511) / 512, 512, 0, stream>>>(cnt, nN);
            int nTiles = (nE + EPB - 1) / EPB;
            edge_k<<<dim3(nTiles, 2), 512, 0, stream>>>(
                x, eidx, ea, W1, b1, g1, be1, m1, v1,
                W2, b2, g2, be2, m2, v2, msgb, cnt, bucket, nE);
            gather_k<<<(nN + 15) / 16, 512, 0, stream>>>(
                x, root, bias, msgb, bucket, cnt, eidx, out, nN, nE);
        }
    } else {
        // zero-workspace fallback
        root_init_k<<<(nN * OD + 255) / 256, 256, 0, stream>>>(x, root, bias, out, nN);
        edge_raw_k<<<dim3((nE + 63) / 64, 2), 64, 0, stream>>>(
            x, eidx, ea, W1, b1, g1, be1, m1, v1,
            W2, b2, g2, be2, m2, v2, out, nE);
    }
}

// Round 13
// 187.581 us; speedup vs baseline: 2.1265x; 2.1265x over previous
//
#include <hip/hip_runtime.h>
#include <math.h>

// Problem dims (fixed by the reference)
#define ED 16      // EDGE_DIM
#define HD 32      // HIDDEN (== NODE_DIM == in_channels)
#define OD 32      // OUT_DIM
#define KD 1024    // HD*OD
#define EPB 512    // edges per block (8 waves, one o-half per block)
#define TPW 4      // 16-edge MFMA tiles per wave
#define HPAD 34    // LDS row stride (halfwords): odd word-stride -> conflict-free
#define CAP 32     // bucket capacity per node (deg ~ Poisson(4))

typedef float  f32x4  __attribute__((ext_vector_type(4)));
typedef float  v4f    __attribute__((ext_vector_type(4)));
typedef short  bf16x8 __attribute__((ext_vector_type(8)));
typedef short  bf16x4 __attribute__((ext_vector_type(4)));

// LDS layout (edge kernel)
constexpr int LOFF_HX  = 0;                      // hHi [EPB][HPAD] hw; xS overlay
constexpr int LOFF_WHI = EPB * HPAD * 2;         // 34816: wLhi 32 KB (o-half frags)
constexpr int LOFF_W1T = LOFF_WHI + 32768;       // 67584: W1fT 2048 B
constexpr int LOFF_B1  = LOFF_W1T + 2048;        // 69632: b1f 128 B
constexpr int LOFF_BF  = LOFF_B1 + 128;          // 69760: bfold half 2048 B
constexpr int LOFF_DST = LOFF_BF + 2048;         // 71808: dstS 2048 B
constexpr int LDS_TOTAL= LOFF_DST + 2048;        // 73856 B -> 2 blocks/CU

__device__ inline unsigned short bf16_rne(float v) {
    unsigned int u = __float_as_uint(v);
    return (unsigned short)((u + 0x7FFFu + ((u >> 16) & 1u)) >> 16);
}

// ---------------------------------------------------------------------------
// Per-block weight fold: raw W1/W2 + BN params (global, L2-hot after first
// touch; W2 is only 128 KB) -> LDS frag layout. o-half s only.
// ---------------------------------------------------------------------------
__device__ __forceinline__ void stage_weights(
    int t, int s, unsigned char* smem,
    const float* __restrict__ W1, const float* __restrict__ b1,
    const float* __restrict__ g1, const float* __restrict__ be1,
    const float* __restrict__ m1, const float* __restrict__ v1,
    const float* __restrict__ W2, const float* __restrict__ b2,
    const float* __restrict__ g2, const float* __restrict__ be2,
    const float* __restrict__ m2, const float* __restrict__ v2)
{
    float* w1t = (float*)(smem + LOFF_W1T);
    float* b1s = (float*)(smem + LOFF_B1);
    float* bfL = (float*)(smem + LOFF_BF);
    unsigned short* wLhi = (unsigned short*)(smem + LOFF_WHI);

    {   // W1fT [c][j], 512 entries, one per thread
        int c = t >> 4, j = t & 15;
        float sc = g1[c] / sqrtf(v1[c] + 1e-5f);
        w1t[t] = W1[j * HD + c] * sc;
    }
    if (t < HD) {
        float sc = g1[t] / sqrtf(v1[t] + 1e-5f);
        b1s[t] = b1[t] * sc + be1[t] - m1[t] * sc;
    }
    {   // bfold half: bfL[i*16+m], k = (2i+s)*16+m
        int i = t >> 4, m = t & 15;
        int k = (2 * i + s) * 16 + m;
        float sc = g2[k] / sqrtf(v2[k] + 1e-5f);
        bfL[t] = b2[k] * sc + be2[k] - m2[k] * sc;
    }
#pragma unroll
    for (int p = 0; p < 4; ++p) {   // wLhi frag-linear, 4 x 8-bf16 chunks/thread
        int c = t + p * 512;                       // chunk: i = c>>6, lane = c&63
        int i = c >> 6, ln = c & 63;
        int m = ln & 15, quad = ln >> 4;
        int k = (2 * i + s) * 16 + m;
        float sc = g2[k] / sqrtf(v2[k] + 1e-5f);
        bf16x8 w;
#pragma unroll
        for (int idx = 0; idx < 8; ++idx) {
            int j = quad * 8 + idx;
            w[idx] = (short)bf16_rne(W2[j * KD + k] * sc);
        }
        *(bf16x8*)(wLhi + (size_t)c * 8) = w;
    }
}

// ---------------------------------------------------------------------------
// One 512-edge tile: layer1 -> bf16 h in LDS -> MFMA loop -> bf16 msg store
// + bucket insert (owner: s==0 && quad==0). Weights must be staged.
// ---------------------------------------------------------------------------
__device__ __forceinline__ void edge_tile(
    int t, int s, int tileBase, unsigned char* smem,
    const float* __restrict__ x, const int* __restrict__ eidx,
    const float* __restrict__ ea_g,
    unsigned short* __restrict__ msgb, int* __restrict__ cnt,
    int* __restrict__ bucket, int nE)
{
    unsigned short* hHi = (unsigned short*)(smem + LOFF_HX);
    unsigned short* xS  = (unsigned short*)(smem + LOFF_HX);   // overlay
    const unsigned short* wLhi = (const unsigned short*)(smem + LOFF_WHI);
    const float* w1t = (const float*)(smem + LOFF_W1T);
    const float* b1s = (const float*)(smem + LOFF_B1);
    const float* bfL = (const float*)(smem + LOFF_BF);
    int* dstS = (int*)(smem + LOFF_DST);

    int e = tileBase + t;
    int ec = (e < nE) ? e : (nE - 1);
    int my_src = __builtin_nontemporal_load(eidx + ec);
    int my_dst = __builtin_nontemporal_load(eidx + nE + ec);

    const v4f* xrow_p = (const v4f*)(x + (size_t)my_src * HD);
    v4f xrow[8];
#pragma unroll
    for (int q = 0; q < 8; ++q) xrow[q] = xrow_p[q];

    const v4f* eap = (const v4f*)(ea_g + (size_t)ec * ED);
    v4f a0 = __builtin_nontemporal_load(eap + 0);
    v4f a1 = __builtin_nontemporal_load(eap + 1);
    v4f a2 = __builtin_nontemporal_load(eap + 2);
    v4f a3 = __builtin_nontemporal_load(eap + 3);

    dstS[t] = my_dst;

    // ---- layer 1 ----
    float hreg[HD];
#pragma unroll
    for (int c = 0; c < HD; ++c) {
        const v4f* r4 = (const v4f*)(w1t + c * ED);
        v4f w0 = r4[0], w1 = r4[1], w2 = r4[2], w3 = r4[3];
        float acc = b1s[c];
        acc = fmaf(a0.x, w0.x, acc); acc = fmaf(a0.y, w0.y, acc);
        acc = fmaf(a0.z, w0.z, acc); acc = fmaf(a0.w, w0.w, acc);
        acc = fmaf(a1.x, w1.x, acc); acc = fmaf(a1.y, w1.y, acc);
        acc = fmaf(a1.z, w1.z, acc); acc = fmaf(a1.w, w1.w, acc);
        acc = fmaf(a2.x, w2.x, acc); acc = fmaf(a2.y, w2.y, acc);
        acc = fmaf(a2.z, w2.z, acc); acc = fmaf(a2.w, w2.w, acc);
        acc = fmaf(a3.x, w3.x, acc); acc = fmaf(a3.y, w3.y, acc);
        acc = fmaf(a3.z, w3.z, acc); acc = fmaf(a3.w, w3.w, acc);
        hreg[c] = fmaxf(acc, 0.01f * acc);
    }

#pragma unroll
    for (int ch = 0; ch < 4; ++ch) {
        bf16x8 phi;
#pragma unroll
        for (int u = 0; u < 8; ++u)
            phi[u] = (short)bf16_rne(hreg[ch * 8 + u]);
        *(bf16x8*)(hHi + t * HPAD + ch * 8) = phi;
    }
    __syncthreads();   // h ready

    const int wave = t >> 6;
    const int lane = t & 63;
    const int n = lane & 15;
    const int quad = lane >> 4;
    const int ebase = wave * 64;

    bf16x8 bHi[TPW];
#pragma unroll
    for (int tt = 0; tt < TPW; ++tt) {
        int edge = ebase + tt * 16 + n;
        bHi[tt] = *(const bf16x8*)(hHi + edge * HPAD + quad * 8);
    }

    int xdst[TPW];
    bool evalid[TPW];
    int xoff[TPW];
    int geid[TPW];
#pragma unroll
    for (int tt = 0; tt < TPW; ++tt) {
        int le = ebase + tt * 16 + n;
        geid[tt] = tileBase + le;
        evalid[tt] = geid[tt] < nE;
        xdst[tt] = dstS[le];
        xoff[tt] = le * HPAD;
    }

    __syncthreads();   // h reads done; overlay safe

#pragma unroll
    for (int ch = 0; ch < 4; ++ch) {
        bf16x8 px;
#pragma unroll
        for (int u = 0; u < 8; ++u) {
            int q = ch * 2 + (u >> 2);
            px[u] = (short)bf16_rne(xrow[q][u & 3]);
        }
        *(bf16x8*)(xS + t * HPAD + ch * 8) = px;
    }
    __syncthreads();   // xS ready

    f32x4 msg[TPW];
#pragma unroll
    for (int tt = 0; tt < TPW; ++tt)
        msg[tt] = (f32x4){0.f, 0.f, 0.f, 0.f};

#pragma unroll 4
    for (int i = 0; i < HD; ++i) {
        const bf16x8 cH = *(const bf16x8*)(wLhi + i * 512 + lane * 8);
        const f32x4 b0 = *(const f32x4*)(bfL + i * 16 + quad * 4);
        float xv[TPW];
#pragma unroll
        for (int tt = 0; tt < TPW; ++tt) {
            unsigned int u = xS[xoff[tt] + i];
            xv[tt] = __uint_as_float(u << 16);
        }
#pragma unroll
        for (int tt = 0; tt < TPW; ++tt) {
            f32x4 c = b0;
            c = __builtin_amdgcn_mfma_f32_16x16x32_bf16(cH, bHi[tt], c, 0, 0, 0);
            f32x4 w = __builtin_elementwise_max(c, 0.01f * c);   // LeakyReLU
            f32x4 xs = {xv[tt], xv[tt], xv[tt], xv[tt]};
            msg[tt] = __builtin_elementwise_fma(xs, w, msg[tt]);
        }
    }

#pragma unroll
    for (int tt = 0; tt < TPW; ++tt) {
        if (!evalid[tt]) continue;
        bf16x4 pm;
#pragma unroll
        for (int r = 0; r < 4; ++r) pm[r] = (short)bf16_rne(msg[tt][r]);
        __builtin_nontemporal_store(pm,
            (bf16x4*)(msgb + (size_t)geid[tt] * OD + s * 16 + quad * 4));
    }
    if (s == 0 && quad == 0) {
#pragma unroll
        for (int tt = 0; tt < TPW; ++tt) {
            if (!evalid[tt]) continue;
            int pos = atomicAdd(cnt + xdst[tt], 1);
            if (pos < CAP) bucket[(size_t)xdst[tt] * CAP + pos] = geid[tt];
        }
    }
}

// ---------------------------------------------------------------------------
// Edge kernel: inline weight staging (no prep dispatch) + one tile.
// grid = (nTiles, 2); s = blockIdx.y.
// ---------------------------------------------------------------------------
__global__ __launch_bounds__(512, 4)
void edge_k(const float* __restrict__ x, const int* __restrict__ eidx,
            const float* __restrict__ ea,
            const float* __restrict__ W1, const float* __restrict__ b1,
            const float* __restrict__ g1, const float* __restrict__ be1,
            const float* __restrict__ m1, const float* __restrict__ v1,
            const float* __restrict__ W2, const float* __restrict__ b2,
            const float* __restrict__ g2, const float* __restrict__ be2,
            const float* __restrict__ m2, const float* __restrict__ v2,
            unsigned short* msgb, int* cnt, int* bucket, int nE)
{
    __shared__ __align__(16) unsigned char smem[LDS_TOTAL];
    const int t = threadIdx.x;
    const int s = blockIdx.y;
    stage_weights(t, s, smem, W1, b1, g1, be1, m1, v1,
                  W2, b2, g2, be2, m2, v2);
    __syncthreads();
    edge_tile(t, s, (int)blockIdx.x * EPB, smem, x, eidx, ea, msgb, cnt, bucket, nE);
}

// ---------------------------------------------------------------------------
// Gather+root: out[v][ch] = bias + x[v]@root[:,ch] + sum(bucketed msgs).
// 512 threads = 16 nodes/block; writes out exactly once (nt store).
// ---------------------------------------------------------------------------
__global__ __launch_bounds__(512)
void gather_k(const float* __restrict__ x, const float* __restrict__ root,
              const float* __restrict__ bias,
              const unsigned short* __restrict__ msgb,
              const int* __restrict__ bucket, const int* __restrict__ cnt,
              const int* __restrict__ eidx,
              float* __restrict__ out, int nN, int nE)
{
    __shared__ __align__(16) float rootS[HD * OD];
    __shared__ __align__(16) float biasS[OD];
    __shared__ float xsh[16][33];

    const int t = threadIdx.x;
    if (t < 256)      ((v4f*)rootS)[t] = ((const v4f*)root)[t];
    else if (t < 264) ((v4f*)biasS)[t - 256] = ((const v4f*)bias)[t - 256];

    const int nodeBase = blockIdx.x * 16;
    if (t < 128) {
        int nl = t >> 3, q = t & 7;
        int node = nodeBase + nl;
        if (node >= nN) node = nN - 1;
        v4f v = ((const v4f*)(x + (size_t)node * HD))[q];
        xsh[nl][4 * q + 0] = v.x;
        xsh[nl][4 * q + 1] = v.y;
        xsh[nl][4 * q + 2] = v.z;
        xsh[nl][4 * q + 3] = v.w;
    }
    __syncthreads();

    const int nl = t >> 5, ch = t & 31;
    const int v = nodeBase + nl;
    if (v >= nN) return;

    float acc = biasS[ch];
#pragma unroll
    for (int i = 0; i < HD; ++i)
        acc = fmaf(xsh[nl][i], rootS[i * OD + ch], acc);

    int c = cnt[v];
    if (c <= CAP) {
        const int* bk = bucket + (size_t)v * CAP;
        for (int p = 0; p < c; ++p) {
            int e = bk[p];
            unsigned int u = msgb[(size_t)e * OD + ch];
            acc += __uint_as_float(u << 16);
        }
    } else {   // pathological overflow: rescan dst list
        const int* dstp = eidx + nE;
        for (int e = 0; e < nE; ++e)
            if (dstp[e] == v) {
                unsigned int u = msgb[(size_t)e * OD + ch];
                acc += __uint_as_float(u << 16);
            }
    }
    __builtin_nontemporal_store(acc, out + (size_t)v * OD + ch);
}

// ---------------------------------------------------------------------------
// Zero-workspace fallback: raw per-edge VALU path with direct atomics.
// ---------------------------------------------------------------------------
__global__ void root_init_k(const float* __restrict__ x, const float* __restrict__ root,
                            const float* __restrict__ bias, float* __restrict__ out, int nN)
{
    int t = blockIdx.x * blockDim.x + threadIdx.x;
    if (t >= nN * OD) return;
    int o = t & (OD - 1);
    int n = t >> 5;
    const float* xr = x + (size_t)n * HD;
    float acc = bias[o];
#pragma unroll
    for (int i = 0; i < HD; ++i)
        acc = fmaf(xr[i], root[i * OD + o], acc);
    out[t] = acc;
}

__global__ __launch_bounds__(64)
void edge_raw_k(const float* __restrict__ x, const int* __restrict__ eidx,
                const float* __restrict__ ea_g,
                const float* __restrict__ W1, const float* __restrict__ b1,
                const float* __restrict__ g1, const float* __restrict__ be1,
                const float* __restrict__ m1, const float* __restrict__ v1,
                const float* __restrict__ W2, const float* __restrict__ b2,
                const float* __restrict__ g2, const float* __restrict__ be2,
                const float* __restrict__ m2, const float* __restrict__ v2,
                float* __restrict__ out, int nE)
{
    int e = blockIdx.x * 64 + threadIdx.x;
    if (e >= nE) return;
    const int obase = blockIdx.y * 16;
    int src = eidx[e];
    int dst = eidx[nE + e];
    float eav[ED];
#pragma unroll
    for (int j = 0; j < ED; ++j) eav[j] = ea_g[(size_t)e * ED + j];
    float h[HD];
#pragma unroll
    for (int c = 0; c < HD; ++c) {
        float acc = b1[c];
#pragma unroll
        for (int j = 0; j < ED; ++j) acc = fmaf(eav[j], W1[j * HD + c], acc);
        float sc = g1[c] / sqrtf(v1[c] + 1e-5f);
        acc = (acc - m1[c]) * sc + be1[c];
        h[c] = fmaxf(acc, 0.01f * acc);
    }
    float msg[16];
#pragma unroll
    for (int o = 0; o < 16; ++o) msg[o] = 0.f;
    const float* xj = x + (size_t)src * HD;
    for (int i = 0; i < HD; ++i) {
        float xv = xj[i];
#pragma unroll
        for (int oo = 0; oo < 16; ++oo) {
            int k = i * OD + obase + oo;
            float acc = b2[k];
#pragma unroll
            for (int j = 0; j < HD; ++j) acc = fmaf(h[j], W2[j * KD + k], acc);
            float sc = g2[k] / sqrtf(v2[k] + 1e-5f);
            acc = (acc - m2[k]) * sc + be2[k];
            float w = fmaxf(acc, 0.01f * acc);
            msg[oo] = fmaf(xv, w, msg[oo]);
        }
    }
    float* op = out + (size_t)dst * OD + obase;
#pragma unroll
    for (int oo = 0; oo < 16; ++oo) atomicAdd(op + oo, msg[oo]);
}

// ---------------------------------------------------------------------------
extern "C" void kernel_launch(void* const* d_in, const int* in_sizes, int n_in,
                              void* d_out, int out_size, void* d_ws, size_t ws_size,
                              hipStream_t stream)
{
    const float* x    = (const float*)d_in[0];
    const int*   eidx = (const int*)  d_in[1];
    const float* ea   = (const float*)d_in[2];
    const float* W1   = (const float*)d_in[4];
    const float* b1   = (const float*)d_in[5];
    const float* g1   = (const float*)d_in[6];
    const float* be1  = (const float*)d_in[7];
    const float* m1   = (const float*)d_in[8];
    const float* v1   = (const float*)d_in[9];
    const float* W2   = (const float*)d_in[10];
    const float* b2   = (const float*)d_in[11];
    const float* g2   = (const float*)d_in[12];
    const float* be2  = (const float*)d_in[13];
    const float* m2   = (const float*)d_in[14];
    const float* v2   = (const float*)d_in[15];
    const float* root = (const float*)d_in[16];
    const float* bias = (const float*)d_in[17];
    float* out = (float*)d_out;

    int nN = in_sizes[0] / HD;
    int nE = in_sizes[2] / ED;

    size_t msgB = (size_t)nE * OD * 2;                     // bf16 msg
    size_t OFF_BKT = (msgB + 15) & ~(size_t)15;
    size_t OFF_CNT = OFF_BKT + (size_t)nN * CAP * 4;
    size_t need = OFF_CNT + (size_t)nN * 4;

    if (ws_size >= need) {
        unsigned char* wsb = (unsigned char*)d_ws;
        unsigned short* msgb = (unsigned short*)wsb;
        int* bucket = (int*)(wsb + OFF_BKT);
        int* cnt    = (int*)(wsb + OFF_CNT);

        hipMemsetAsync(cnt, 0, (size_t)nN * 4, stream);
        int nTiles = (nE + EPB - 1) / EPB;
        edge_k<<<dim3(nTiles, 2), 512, 0, stream>>>(
            x, eidx, ea, W1, b1, g1, be1, m1, v1,
            W2, b2, g2, be2, m2, v2, msgb, cnt, bucket, nE);
        gather_k<<<(nN + 15) / 16, 512, 0, stream>>>(
            x, root, bias, msgb, bucket, cnt, eidx, out, nN, nE);
    } else {
        root_init_k<<<(nN * OD + 255) / 256, 256, 0, stream>>>(x, root, bias, out, nN);
        edge_raw_k<<<dim3((nE + 63) / 64, 2), 64, 0, stream>>>(
            x, eidx, ea, W1, b1, g1, be1, m1, v1,
            W2, b2, g2, be2, m2, v2, out, nE);
    }
}

// Round 14
// 170.859 us; speedup vs baseline: 2.3347x; 1.0979x over previous
//
#include <hip/hip_runtime.h>
#include <math.h>

// Problem dims (fixed by the reference)
#define ED 16      // EDGE_DIM
#define HD 32      // HIDDEN (== NODE_DIM == in_channels)
#define OD 32      // OUT_DIM
#define KD 1024    // HD*OD
#define EPB 256    // edges per block (512 threads, both o-halves)
#define TPW 2      // 16-edge MFMA tiles per wave (wave owns 32 edges)
#define HPAD 34    // LDS row stride in halfwords (68 B rows, conflict-benign)
#define CAP 32     // bucket capacity per node (deg ~ Poisson(4))

typedef float  f32x4  __attribute__((ext_vector_type(4)));
typedef float  v4f    __attribute__((ext_vector_type(4)));
typedef short  bf16x8 __attribute__((ext_vector_type(8)));
typedef short  bf16x4 __attribute__((ext_vector_type(4)));

// Workspace layout (byte offsets; all 16B aligned)
//  [0)     W1fT 512 f32 ; [2048) b1f 32 f32 ; [2176) bfold 1024 f32
//  [6272)  wsAhi 32768 bf16 W2fT hi (RNE), frag-linear
//  [72064) msg [nE][32] bf16 (channel-permuted: idx = quad*8 + s*4 + r)
//  then    bucket [nN][CAP] int ; cnt [nN] int
constexpr size_t OFF_MSG = 72064;

// LDS layout (edge kernel): 57472 B -> 2 blocks/CU, 16 waves/CU.
constexpr int LOFF_HX  = 0;                 // eaS f32[256][17] -> hHi hw[256][34] -> xS bf16 overlay
constexpr int LOFF_WHI = 17408;             // wLhi 32768 B (one o-half)
constexpr int LOFF_W1T = LOFF_WHI + 32768;  // 50176: 2048 B
constexpr int LOFF_B1  = LOFF_W1T + 2048;   // 52224: 128 B
constexpr int LOFF_BF  = LOFF_B1 + 128;     // 52352: [2][512] f32 = 4096 B
constexpr int LOFF_DST = LOFF_BF + 4096;    // 56448: 1024 B
constexpr int LDS_TOTAL= LOFF_DST + 1024;   // 57472 B

__device__ inline unsigned short bf16_rne(float v) {
    unsigned int u = __float_as_uint(v);
    return (unsigned short)((u + 0x7FFFu + ((u >> 16) & 1u)) >> 16);
}

// ---------------------------------------------------------------------------
// Prep: fold BN into W1fT/b1f/bfold/wsAhi (frag-linear bf16 RNE) + zero cnt.
// W2 traversed source-linear (coalesced reads, scattered 2B writes).
// ---------------------------------------------------------------------------
__global__ __launch_bounds__(256)
void prep_kernel(const float* __restrict__ W1, const float* __restrict__ b1,
                 const float* __restrict__ g1, const float* __restrict__ be1,
                 const float* __restrict__ m1, const float* __restrict__ v1,
                 const float* __restrict__ W2, const float* __restrict__ b2,
                 const float* __restrict__ g2, const float* __restrict__ be2,
                 const float* __restrict__ m2, const float* __restrict__ v2,
                 unsigned char* __restrict__ wsb, int* __restrict__ cnt, int nN)
{
    float* w1t = (float*)(wsb);
    float* b1f = (float*)(wsb + 2048);
    float* bf  = (float*)(wsb + 2176);
    unsigned short* ahi = (unsigned short*)(wsb + 6272);

    int bt = blockIdx.x * blockDim.x + threadIdx.x;
    int stride = gridDim.x * blockDim.x;

    for (int q = bt; q < nN; q += stride) cnt[q] = 0;

    for (int q = bt; q < HD * ED; q += stride) {       // W1fT [c][j]
        int c = q >> 4, j = q & 15;
        float s = g1[c] / sqrtf(v1[c] + 1e-5f);
        w1t[q] = W1[j * HD + c] * s;
    }
    for (int c = bt; c < HD; c += stride) {
        float s = g1[c] / sqrtf(v1[c] + 1e-5f);
        b1f[c] = b1[c] * s + be1[c] - m1[c] * s;
    }
    for (int k = bt; k < KD; k += stride) {
        float s = g2[k] / sqrtf(v2[k] + 1e-5f);
        bf[k] = b2[k] * s + be2[k] - m2[k] * s;
    }
    for (int p = bt; p < KD * HD; p += stride) {       // p = j*KD + k
        int j = p >> 10, k = p & 1023;
        float s = g2[k] / sqrtf(v2[k] + 1e-5f);
        float v = W2[p] * s;
        int g = k >> 4, m = k & 15;
        int quad = j >> 3, idx = j & 7;
        int q = g * 512 + (quad * 16 + m) * 8 + idx;   // frag-linear dest
        ahi[q] = bf16_rne(v);
    }
}

// ---------------------------------------------------------------------------
// Edge kernel v14: 512 threads, 256 edges, BOTH o-halves per block.
//  - ea staged in LDS (read once per edge, shared by the layer-1 thread pair)
//  - layer1 split: thread t computes channels [(t>>8)*16, +16) of edge t&255
//  - h packed once; main loop per half (restage 32KB weights from prefolded
//    ws between halves, coalesced); combined 16B msg store per (edge,quad).
//  msg channel-permuted: buffer idx = quad*8 + s*4 + r (gather un-permutes).
// ---------------------------------------------------------------------------
__global__ __launch_bounds__(512, 4)
void edge_k(const float* __restrict__ x, const int* __restrict__ eidx,
            const float* __restrict__ ea_g, const unsigned char* __restrict__ wsb,
            unsigned short* __restrict__ msgb, int* __restrict__ cnt,
            int* __restrict__ bucket, int nE)
{
    __shared__ __align__(16) unsigned char smem[LDS_TOTAL];
    float*          eaS = (float*)(smem + LOFF_HX);            // [256][17] f32
    unsigned short* hHi = (unsigned short*)(smem + LOFF_HX);   // [256][34] hw (after ea dead)
    unsigned short* xS  = (unsigned short*)(smem + LOFF_HX);   // bf16 x overlay (after h dead)
    unsigned short* wLhi = (unsigned short*)(smem + LOFF_WHI); // [32][64][8]
    float* w1t = (float*)(smem + LOFF_W1T);
    float* b1s = (float*)(smem + LOFF_B1);
    float* bfL = (float*)(smem + LOFF_BF);                     // [2][512]
    int*  dstS = (int*)(smem + LOFF_DST);

    const int t = threadIdx.x;
    const int el = t & 255;          // edge lane
    const int chalf = t >> 8;        // layer-1 channel half (0/1)
    const int tileBase = (int)blockIdx.x * EPB;

    const float* wsW1 = (const float*)(wsb);
    const float* wsB1 = (const float*)(wsb + 2048);
    const v4f*   wsBf4 = (const v4f*)(wsb + 2176);
    const v4f*   srcHi = (const v4f*)(wsb + 6272);

    // ---- per-edge input loads (chalf==0 owns the edge's loads) ----
    int e = tileBase + el;
    int ec = (e < nE) ? e : (nE - 1);
    v4f xrow[8];
    if (chalf == 0) {
        int my_src = __builtin_nontemporal_load(eidx + ec);
        dstS[el] = __builtin_nontemporal_load(eidx + nE + ec);
        const v4f* xrow_p = (const v4f*)(x + (size_t)my_src * HD);
#pragma unroll
        for (int q = 0; q < 8; ++q) xrow[q] = xrow_p[q];
        const v4f* eap = (const v4f*)(ea_g + (size_t)ec * ED);
        v4f a0 = __builtin_nontemporal_load(eap + 0);
        v4f a1 = __builtin_nontemporal_load(eap + 1);
        v4f a2 = __builtin_nontemporal_load(eap + 2);
        v4f a3 = __builtin_nontemporal_load(eap + 3);
        float* er = eaS + el * 17;
        er[0]=a0.x; er[1]=a0.y; er[2]=a0.z; er[3]=a0.w;
        er[4]=a1.x; er[5]=a1.y; er[6]=a1.z; er[7]=a1.w;
        er[8]=a2.x; er[9]=a2.y; er[10]=a2.z; er[11]=a2.w;
        er[12]=a3.x; er[13]=a3.y; er[14]=a3.z; er[15]=a3.w;
    }

    // ---- stage tables (coalesced from prefolded ws) ----
    if (t < 256) {       // bfold both halves: bfL[s][i*16+m] = bfold[i*32+s*16+m]
        int d = t & 127, sh = t >> 7;
        ((v4f*)bfL)[sh * 128 + d] = wsBf4[(d >> 2) * 8 + sh * 4 + (d & 3)];
    } else if (t < 384) {
        ((v4f*)w1t)[t - 256] = ((const v4f*)wsW1)[t - 256];
    } else if (t < 392) {
        ((v4f*)b1s)[t - 384] = ((const v4f*)wsB1)[t - 384];
    }
    // ---- stage o-half 0 weights: 4 v4f per thread (32 KB) ----
    {
        v4f* dstHi = (v4f*)wLhi;
#pragma unroll
        for (int p = 0; p < 4; ++p) {
            int c = t + p * 512;                          // dst: i = c>>6, lane = c&63
            int sc = (2 * (c >> 6) + 0) * 64 + (c & 63);  // src: g*64 + lane
            dstHi[c] = srcHi[sc];
        }
    }
    __syncthreads();   // (1) eaS + tables + wLhi(s=0) ready

    // ---- layer 1: 16 channels per thread ----
    const float* eaR = eaS + el * 17;
    float ea0 = eaR[0], ea1 = eaR[1], ea2 = eaR[2], ea3 = eaR[3];
    float ea4 = eaR[4], ea5 = eaR[5], ea6 = eaR[6], ea7 = eaR[7];
    float ea8 = eaR[8], ea9 = eaR[9], ea10 = eaR[10], ea11 = eaR[11];
    float ea12 = eaR[12], ea13 = eaR[13], ea14 = eaR[14], ea15 = eaR[15];
    const int c0 = chalf * 16;
    float hreg[16];
#pragma unroll
    for (int cc = 0; cc < 16; ++cc) {
        const int c = c0 + cc;
        const v4f* r4 = (const v4f*)(w1t + c * ED);
        v4f w0 = r4[0], w1 = r4[1], w2 = r4[2], w3 = r4[3];
        float acc = b1s[c];
        acc = fmaf(ea0,  w0.x, acc); acc = fmaf(ea1,  w0.y, acc);
        acc = fmaf(ea2,  w0.z, acc); acc = fmaf(ea3,  w0.w, acc);
        acc = fmaf(ea4,  w1.x, acc); acc = fmaf(ea5,  w1.y, acc);
        acc = fmaf(ea6,  w1.z, acc); acc = fmaf(ea7,  w1.w, acc);
        acc = fmaf(ea8,  w2.x, acc); acc = fmaf(ea9,  w2.y, acc);
        acc = fmaf(ea10, w2.z, acc); acc = fmaf(ea11, w2.w, acc);
        acc = fmaf(ea12, w3.x, acc); acc = fmaf(ea13, w3.y, acc);
        acc = fmaf(ea14, w3.z, acc); acc = fmaf(ea15, w3.w, acc);
        hreg[cc] = fmaxf(acc, 0.01f * acc);
    }
    __syncthreads();   // (2) all eaS reads done; hHi overlay safe

    // ---- pack h (2 chunks per thread) ----
#pragma unroll
    for (int ch = 0; ch < 2; ++ch) {
        bf16x8 phi;
#pragma unroll
        for (int u = 0; u < 8; ++u)
            phi[u] = (short)bf16_rne(hreg[ch * 8 + u]);
        *(bf16x8*)(hHi + el * HPAD + c0 + ch * 8) = phi;
    }
    __syncthreads();   // (3) h ready

    // ---- B-frags LDS -> regs; per-tile metadata ----
    const int wave = t >> 6;
    const int lane = t & 63;
    const int n = lane & 15;
    const int quad = lane >> 4;
    const int ebase = wave * 32;     // wave owns 32 edges

    bf16x8 bHi[TPW];
    int xdst[TPW]; bool evalid[TPW]; int xoff[TPW]; int geid[TPW];
#pragma unroll
    for (int tt = 0; tt < TPW; ++tt) {
        int le = ebase + tt * 16 + n;
        bHi[tt] = *(const bf16x8*)(hHi + le * HPAD + quad * 8);
        geid[tt] = tileBase + le;
        evalid[tt] = geid[tt] < nE;
        xdst[tt] = dstS[le];
        xoff[tt] = le * HPAD;
    }
    __syncthreads();   // (4) h consumed; xS overlay safe

    if (chalf == 0) {   // x rows -> bf16 xS
#pragma unroll
        for (int ch = 0; ch < 4; ++ch) {
            bf16x8 px;
#pragma unroll
            for (int u = 0; u < 8; ++u) {
                int q = ch * 2 + (u >> 2);
                px[u] = (short)bf16_rne(xrow[q][u & 3]);
            }
            *(bf16x8*)(xS + el * HPAD + ch * 8) = px;
        }
    }
    __syncthreads();   // (5) xS ready

    // ---- main loop, s = 0 ----
    f32x4 msg[TPW];
#pragma unroll
    for (int tt = 0; tt < TPW; ++tt) msg[tt] = (f32x4){0.f, 0.f, 0.f, 0.f};
#pragma unroll 4
    for (int i = 0; i < HD; ++i) {
        const bf16x8 cH = *(const bf16x8*)(wLhi + i * 512 + lane * 8);
        const f32x4 b0 = *(const f32x4*)(bfL + i * 16 + quad * 4);
        float xv[TPW];
#pragma unroll
        for (int tt = 0; tt < TPW; ++tt) {
            unsigned int u = xS[xoff[tt] + i];
            xv[tt] = __uint_as_float(u << 16);
        }
#pragma unroll
        for (int tt = 0; tt < TPW; ++tt) {
            f32x4 c = b0;
            c = __builtin_amdgcn_mfma_f32_16x16x32_bf16(cH, bHi[tt], c, 0, 0, 0);
            f32x4 w = __builtin_elementwise_max(c, 0.01f * c);
            f32x4 xs = {xv[tt], xv[tt], xv[tt], xv[tt]};
            msg[tt] = __builtin_elementwise_fma(xs, w, msg[tt]);
        }
    }
    bf16x4 pm0[TPW];
#pragma unroll
    for (int tt = 0; tt < TPW; ++tt) {
#pragma unroll
        for (int r = 0; r < 4; ++r) pm0[tt][r] = (short)bf16_rne(msg[tt][r]);
    }

    // bucket insert (once per edge: quad==0 lanes; each wave owns distinct edges)
    if (quad == 0) {
#pragma unroll
        for (int tt = 0; tt < TPW; ++tt) {
            if (!evalid[tt]) continue;
            int pos = atomicAdd(cnt + xdst[tt], 1);
            if (pos < CAP) bucket[(size_t)xdst[tt] * CAP + pos] = geid[tt];
        }
    }

    __syncthreads();   // (6) wLhi s=0 consumed
    {   // restage o-half 1 weights
        v4f* dstHi = (v4f*)wLhi;
#pragma unroll
        for (int p = 0; p < 4; ++p) {
            int c = t + p * 512;
            int sc = (2 * (c >> 6) + 1) * 64 + (c & 63);
            dstHi[c] = srcHi[sc];
        }
    }
    __syncthreads();   // (7) wLhi s=1 ready

    // ---- main loop, s = 1 ----
#pragma unroll
    for (int tt = 0; tt < TPW; ++tt) msg[tt] = (f32x4){0.f, 0.f, 0.f, 0.f};
#pragma unroll 4
    for (int i = 0; i < HD; ++i) {
        const bf16x8 cH = *(const bf16x8*)(wLhi + i * 512 + lane * 8);
        const f32x4 b0 = *(const f32x4*)(bfL + 512 + i * 16 + quad * 4);
        float xv[TPW];
#pragma unroll
        for (int tt = 0; tt < TPW; ++tt) {
            unsigned int u = xS[xoff[tt] + i];
            xv[tt] = __uint_as_float(u << 16);
        }
#pragma unroll
        for (int tt = 0; tt < TPW; ++tt) {
            f32x4 c = b0;
            c = __builtin_amdgcn_mfma_f32_16x16x32_bf16(cH, bHi[tt], c, 0, 0, 0);
            f32x4 w = __builtin_elementwise_max(c, 0.01f * c);
            f32x4 xs = {xv[tt], xv[tt], xv[tt], xv[tt]};
            msg[tt] = __builtin_elementwise_fma(xs, w, msg[tt]);
        }
    }

    // ---- combined 16B store per (edge, quad): [quad*8 + s*4 + r] ----
#pragma unroll
    for (int tt = 0; tt < TPW; ++tt) {
        if (!evalid[tt]) continue;
        bf16x8 pm;
#pragma unroll
        for (int r = 0; r < 4; ++r) {
            pm[r]     = pm0[tt][r];
            pm[4 + r] = (short)bf16_rne(msg[tt][r]);
        }
        __builtin_nontemporal_store(pm,
            (bf16x8*)(msgb + (size_t)geid[tt] * OD + quad * 8));
    }
}

// ---------------------------------------------------------------------------
// Gather+root: out[v][ch] = bias + x[v]@root[:,ch] + sum(bucketed msgs).
// msg buffer is channel-permuted; un-permute: b = quad*8 + s*4 + r.
// ---------------------------------------------------------------------------
__global__ __launch_bounds__(512)
void gather_k(const float* __restrict__ x, const float* __restrict__ root,
              const float* __restrict__ bias,
              const unsigned short* __restrict__ msgb,
              const int* __restrict__ bucket, const int* __restrict__ cnt,
              const int* __restrict__ eidx,
              float* __restrict__ out, int nN, int nE)
{
    __shared__ __align__(16) float rootS[HD * OD];
    __shared__ __align__(16) float biasS[OD];
    __shared__ float xsh[16][33];

    const int t = threadIdx.x;
    if (t < 256)      ((v4f*)rootS)[t] = ((const v4f*)root)[t];
    else if (t < 264) ((v4f*)biasS)[t - 256] = ((const v4f*)bias)[t - 256];

    const int nodeBase = blockIdx.x * 16;
    if (t < 128) {
        int nl = t >> 3, q = t & 7;
        int node = nodeBase + nl;
        if (node >= nN) node = nN - 1;
        v4f v = ((const v4f*)(x + (size_t)node * HD))[q];
        xsh[nl][4 * q + 0] = v.x;
        xsh[nl][4 * q + 1] = v.y;
        xsh[nl][4 * q + 2] = v.z;
        xsh[nl][4 * q + 3] = v.w;
    }
    __syncthreads();

    const int nl = t >> 5, ch = t & 31;
    const int v = nodeBase + nl;
    if (v >= nN) return;

    // permuted buffer index for this logical channel
    const int b = (((ch >> 2) & 3) << 3) + ((ch >> 4) << 2) + (ch & 3);

    float acc = biasS[ch];
#pragma unroll
    for (int i = 0; i < HD; ++i)
        acc = fmaf(xsh[nl][i], rootS[i * OD + ch], acc);

    int c = cnt[v];
    if (c <= CAP) {
        const int* bk = bucket + (size_t)v * CAP;
        for (int p = 0; p < c; ++p) {
            int e = bk[p];
            unsigned int u = msgb[(size_t)e * OD + b];
            acc += __uint_as_float(u << 16);
        }
    } else {   // pathological overflow: rescan dst list
        const int* dstp = eidx + nE;
        for (int e = 0; e < nE; ++e)
            if (dstp[e] == v) {
                unsigned int u = msgb[(size_t)e * OD + b];
                acc += __uint_as_float(u << 16);
            }
    }
    __builtin_nontemporal_store(acc, out + (size_t)v * OD + ch);
}

// ---------------------------------------------------------------------------
// Zero-workspace fallback: raw per-edge VALU path with direct atomics.
// ---------------------------------------------------------------------------
__global__ void root_init_k(const float* __restrict__ x, const float* __restrict__ root,
                            const float* __restrict__ bias, float* __restrict__ out, int nN)
{
    int t = blockIdx.x * blockDim.x + threadIdx.x;
    if (t >= nN * OD) return;
    int o = t & (OD - 1);
    int n = t >> 5;
    const float* xr = x + (size_t)n * HD;
    float acc = bias[o];
#pragma unroll
    for (int i = 0; i < HD; ++i)
        acc = fmaf(xr[i], root[i * OD + o], acc);
    out[t] = acc;
}

__global__ __launch_bounds__(64)
void edge_raw_k(const float* __restrict__ x, const int* __restrict__ eidx,
                const float* __restrict__ ea_g,
                const float* __restrict__ W1, const float* __restrict__ b1,
                const float* __restrict__ g1, const float* __restrict__ be1,
                const float* __restrict__ m1, const float* __restrict__ v1,
                const float* __restrict__ W2, const float* __restrict__ b2,
                const float* __restrict__ g2, const float* __restrict__ be2,
                const float* __restrict__ m2, const float* __restrict__ v2,
                float* __restrict__ out, int nE)
{
    int e = blockIdx.x * 64 + threadIdx.x;
    if (e >= nE) return;
    const int obase = blockIdx.y * 16;
    int src = eidx[e];
    int dst = eidx[nE + e];
    float eav[ED];
#pragma unroll
    for (int j = 0; j < ED; ++j) eav[j] = ea_g[(size_t)e * ED + j];
    float h[HD];
#pragma unroll
    for (int c = 0; c < HD; ++c) {
        float acc = b1[c];
#pragma unroll
        for (int j = 0; j < ED; ++j) acc = fmaf(eav[j], W1[j * HD + c], acc);
        float sc = g1[c] / sqrtf(v1[c] + 1e-5f);
        acc = (acc - m1[c]) * sc + be1[c];
        h[c] = fmaxf(acc, 0.01f * acc);
    }
    float msg[16];
#pragma unroll
    for (int o = 0; o < 16; ++o) msg[o] = 0.f;
    const float* xj = x + (size_t)src * HD;
    for (int i = 0; i < HD; ++i) {
        float xv = xj[i];
#pragma unroll
        for (int oo = 0; oo < 16; ++oo) {
            int k = i * OD + obase + oo;
            float acc = b2[k];
#pragma unroll
            for (int j = 0; j < HD; ++j) acc = fmaf(h[j], W2[j * KD + k], acc);
            float sc = g2[k] / sqrtf(v2[k] + 1e-5f);
            acc = (acc - m2[k]) * sc + be2[k];
            float w = fmaxf(acc, 0.01f * acc);
            msg[oo] = fmaf(xv, w, msg[oo]);
        }
    }
    float* op = out + (size_t)dst * OD + obase;
#pragma unroll
    for (int oo = 0; oo < 16; ++oo) atomicAdd(op + oo, msg[oo]);
}

// ---------------------------------------------------------------------------
extern "C" void kernel_launch(void* const* d_in, const int* in_sizes, int n_in,
                              void* d_out, int out_size, void* d_ws, size_t ws_size,
                              hipStream_t stream)
{
    const float* x    = (const float*)d_in[0];
    const int*   eidx = (const int*)  d_in[1];
    const float* ea   = (const float*)d_in[2];
    const float* W1   = (const float*)d_in[4];
    const float* b1   = (const float*)d_in[5];
    const float* g1   = (const float*)d_in[6];
    const float* be1  = (const float*)d_in[7];
    const float* m1   = (const float*)d_in[8];
    const float* v1   = (const float*)d_in[9];
    const float* W2   = (const float*)d_in[10];
    const float* b2   = (const float*)d_in[11];
    const float* g2   = (const float*)d_in[12];
    const float* be2  = (const float*)d_in[13];
    const float* m2   = (const float*)d_in[14];
    const float* v2   = (const float*)d_in[15];
    const float* root = (const float*)d_in[16];
    const float* bias = (const float*)d_in[17];
    float* out = (float*)d_out;

    int nN = in_sizes[0] / HD;
    int nE = in_sizes[2] / ED;

    size_t msgB = (size_t)nE * OD * 2;                 // bf16
    size_t OFF_BKT = (OFF_MSG + msgB + 15) & ~(size_t)15;
    size_t OFF_CNT = OFF_BKT + (size_t)nN * CAP * 4;
    size_t need = OFF_CNT + (size_t)nN * 4;

    if (ws_size >= need) {
        unsigned char* wsb = (unsigned char*)d_ws;
        unsigned short* msgb = (unsigned short*)(wsb + OFF_MSG);
        int* bucket = (int*)(wsb + OFF_BKT);
        int* cnt    = (int*)(wsb + OFF_CNT);

        prep_kernel<<<128, 256, 0, stream>>>(
            W1, b1, g1, be1, m1, v1, W2, b2, g2, be2, m2, v2, wsb, cnt, nN);
        int nTiles = (nE + EPB - 1) / EPB;
        edge_k<<<dim3(nTiles), 512, 0, stream>>>(
            x, eidx, ea, wsb, msgb, cnt, bucket, nE);
        gather_k<<<(nN + 15) / 16, 512, 0, stream>>>(
            x, root, bias, msgb, bucket, cnt, eidx, out, nN, nE);
    } else {
        root_init_k<<<(nN * OD + 255) / 256, 256, 0, stream>>>(x, root, bias, out, nN);
        edge_raw_k<<<dim3((nE + 63) / 64, 2), 64, 0, stream>>>(
            x, eidx, ea, W1, b1, g1, be1, m1, v1,
            W2, b2, g2, be2, m2, v2, out, nE);
    }
}